// Round 8
// baseline (168.915 us; speedup 1.0000x reference)
//
#include <hip/hip_runtime.h>
#include <hip/hip_bf16.h>

#define B_  8
#define C_  384
#define N_  1024
#define NH_ 12
#define HD_ 32
#define D3_ 1152   // 3*C

typedef __bf16 bf16x8 __attribute__((ext_vector_type(8)));
typedef __bf16 bf16x2 __attribute__((ext_vector_type(2)));
typedef float  f32x4  __attribute__((ext_vector_type(4)));

typedef const __attribute__((address_space(1))) unsigned int guint;
typedef __attribute__((address_space(3))) unsigned int luint;

__device__ __forceinline__ float b2f(ushort u) {
    return __uint_as_float(((unsigned int)u) << 16);
}
__device__ __forceinline__ ushort f2b(float f) {
    unsigned int i = __float_as_uint(f);
    unsigned int r = i + 0x7fffu + ((i >> 16) & 1u);  // RNE
    return (ushort)(r >> 16);
}
// packed fp32x2 -> bf16x2 (RNE)
__device__ __forceinline__ unsigned pk2(float a, float b) {
#if __has_builtin(__builtin_amdgcn_cvt_pk_bf16_f32)
    bf16x2 t = __builtin_amdgcn_cvt_pk_bf16_f32(a, b);
    return __builtin_bit_cast(unsigned, t);
#else
    return (unsigned)f2b(a) | ((unsigned)f2b(b) << 16);
#endif
}

#if __has_builtin(__builtin_amdgcn_exp2f)
#define EXP2 __builtin_amdgcn_exp2f
#else
#define EXP2 exp2f
#endif

__device__ __forceinline__ void gl2lds16(const void* g, void* l) {
    __builtin_amdgcn_global_load_lds((guint*)g, (luint*)l, 16, 0, 0);
}

#define C1_ 0.25505654204433796f   // scale * log2e
#define C2_ 1.4426950408889634f    // log2e
#define TS_ 3972                   // padded per-head table stride (16B-aligned)

// ---------------------------------------------------------------------------
// setup: x-transpose + weight conversion + bias-table prep.
// Grid: [0,768) xtrans, [768,1346) prep, [1346,1358) tabT.
// tabT[h][i] = rpb[3968-i][h] * log2e   (full 2D reversal == 1D reversal)
// ---------------------------------------------------------------------------
__global__ __launch_bounds__(256) void setup(
    const float* __restrict__ x, const float* __restrict__ q_w,
    const float* __restrict__ kv_w, const float* __restrict__ proj_w,
    const float* __restrict__ q_b, const float* __restrict__ kv_b,
    const float* __restrict__ tab,
    ushort* __restrict__ xT, float* __restrict__ tabT,
    ushort* __restrict__ Wall, ushort* __restrict__ PW,
    float* __restrict__ ballf)
{
    __shared__ ushort T[64 * 72];
    const int bx = blockIdx.x, tid = threadIdx.x;

    if (bx < 768) {
        // ---- xtrans: x[b][c][n] fp32 -> xT[b][n][c] bf16 ----
        int t = bx;
        int nx = t & 15, cy = (t >> 4) % 6, b = t / 96;
        int n0 = nx * 64, c0 = cy * 64;
        {
            int i = tid >> 2;            // c-local
            int ns = (tid & 3) * 16;     // n-local
            const float* src = x + ((size_t)b * C_ + c0 + i) * N_ + n0 + ns;
            #pragma unroll
            for (int k4 = 0; k4 < 4; ++k4) {
                float4 f = *(const float4*)(src + k4 * 4);
                T[(ns + k4 * 4 + 0) * 72 + i] = f2b(f.x);
                T[(ns + k4 * 4 + 1) * 72 + i] = f2b(f.y);
                T[(ns + k4 * 4 + 2) * 72 + i] = f2b(f.z);
                T[(ns + k4 * 4 + 3) * 72 + i] = f2b(f.w);
            }
        }
        __syncthreads();
        {
            int j = tid >> 2;            // n-local
            int cs = (tid & 3) * 16;     // c-local
            ushort* dst = xT + ((size_t)b * N_ + n0 + j) * C_ + c0 + cs;
            *(uint4*)dst       = *(const uint4*)&T[j * 72 + cs];
            *(uint4*)(dst + 8) = *(const uint4*)&T[j * 72 + cs + 8];
        }
    } else if (bx < 1346) {
        // ---- prep: weights fp32 -> bf16; bias concat fp32 ----
        const int NW4 = 110592, NP4 = 36864, NB4 = 288;
        int t = (bx - 768) * 256 + tid;
        if (t < NW4) {
            int e = t * 4;
            float4 f = (e < 147456) ? *(const float4*)(q_w + e)
                                    : *(const float4*)(kv_w + e - 147456);
            union { uint2 u; ushort s[4]; } o;
            o.u.x = pk2(f.x, f.y); o.u.y = pk2(f.z, f.w);
            *(uint2*)(Wall + e) = o.u;
        } else if (t < NW4 + NP4) {
            int e = (t - NW4) * 4;
            float4 f = *(const float4*)(proj_w + e);
            union { uint2 u; ushort s[4]; } o;
            o.u.x = pk2(f.x, f.y); o.u.y = pk2(f.z, f.w);
            *(uint2*)(PW + e) = o.u;
        } else if (t < NW4 + NP4 + NB4) {
            int e = (t - NW4 - NP4) * 4;
            float4 f = (e < 384) ? *(const float4*)(q_b + e)
                                 : *(const float4*)(kv_b + e - 384);
            *(float4*)(ballf + e) = f;
        }
    } else {
        // ---- tabT: per-head fully-reversed, log2e-scaled table ----
        int h = bx - 1346;
        for (int i = tid; i < 3969; i += 256)
            tabT[h * TS_ + i] = tab[(size_t)(3968 - i) * NH_ + h] * C2_;
        if (tid < 3) tabT[h * TS_ + 3969 + tid] = 0.0f;
    }
}

// ---------------------------------------------------------------------------
// qkv_gemm5: 128x128 tile, global_load_lds, XOR-swizzled LDS.
// Q/K blocks: W as A-operand (C rows = d) -> packed 8B stores to Qt/Kt[b][h][n][32].
// V blocks:   x as A-operand (C rows = n) -> fused-transpose packed stores to Vtc.
// Q pre-scaled by scale*log2e.
// ---------------------------------------------------------------------------
__global__ __launch_bounds__(256) void qkv_gemm5(
    const ushort* __restrict__ xT, const ushort* __restrict__ Wall,
    const float* __restrict__ ballf, ushort* __restrict__ Qt,
    ushort* __restrict__ Kt, ushort* __restrict__ Vtc)
{
    const int b = blockIdx.z, n0 = blockIdx.x * 128, d0 = blockIdx.y * 128;
    __shared__ ushort As[128 * 32];
    __shared__ ushort Bs[128 * 32];
    const int tid = threadIdx.x;
    const int lane = tid & 63, wave = tid >> 6;
    const int quad = lane >> 4, l16 = lane & 15;
    const int wn = (wave & 1) * 64, wd = (wave >> 1) * 64;

    f32x4 acc[4][4] = {};
    const ushort* xb = xT + ((size_t)b * N_ + n0) * C_;
    const ushort* wb = Wall + (size_t)d0 * C_;
    const int rowA = wave * 16 + (lane >> 2);
    const int fstage = ((lane >> 2) ^ (lane >> 4)) & 3;           // staging swizzle
    const int coff = ((lane & 3) ^ fstage) * 8;
    const int fread = ((l16 & 3) ^ ((l16 >> 2) & 3));             // read swizzle
    const bool isV = (d0 >= 768);

    for (int c0 = 0; c0 < C_; c0 += 32) {
        #pragma unroll
        for (int k = 0; k < 2; ++k) {
            gl2lds16(xb + (size_t)(k * 64 + rowA) * C_ + c0 + coff,
                     &As[(size_t)(k * 256 + wave * 64) * 8]);
            gl2lds16(wb + (size_t)(k * 64 + rowA) * C_ + c0 + coff,
                     &Bs[(size_t)(k * 256 + wave * 64) * 8]);
        }
        __syncthreads();
        bf16x8 af[4], bfr[4];
        #pragma unroll
        for (int i = 0; i < 4; ++i)
            af[i] = *(const bf16x8*)&As[(wn + i * 16 + l16) * 32 + (quad ^ fread) * 8];
        #pragma unroll
        for (int j = 0; j < 4; ++j)
            bfr[j] = *(const bf16x8*)&Bs[(wd + j * 16 + l16) * 32 + (quad ^ fread) * 8];
        if (!isV) {
            #pragma unroll
            for (int i = 0; i < 4; ++i)
                #pragma unroll
                for (int j = 0; j < 4; ++j)
                    acc[i][j] = __builtin_amdgcn_mfma_f32_16x16x32_bf16(bfr[i], af[j], acc[i][j], 0, 0, 0);
        } else {
            #pragma unroll
            for (int i = 0; i < 4; ++i)
                #pragma unroll
                for (int j = 0; j < 4; ++j)
                    acc[i][j] = __builtin_amdgcn_mfma_f32_16x16x32_bf16(af[i], bfr[j], acc[i][j], 0, 0, 0);
        }
        __syncthreads();
    }

    if (!isV) {
        ushort* dst = (d0 < 384) ? Qt : Kt;
        const float sc = (d0 < 384) ? C1_ : 1.0f;
        const int reg0 = (d0 < 384) ? 0 : 384;
        #pragma unroll
        for (int i = 0; i < 4; ++i) {
            int dloc = wd + i * 16;
            int dg = d0 - reg0 + dloc;
            int h = dg >> 5;
            int dc = (dg & 31) + quad * 4;
            float4 bvv = *(const float4*)(ballf + d0 + dloc + quad * 4);
            size_t hb = (size_t)(b * NH_ + h) * N_;
            #pragma unroll
            for (int j = 0; j < 4; ++j) {
                int n = n0 + wn + j * 16 + l16;
                uint2 w;
                w.x = pk2((acc[i][j][0] + bvv.x) * sc, (acc[i][j][1] + bvv.y) * sc);
                w.y = pk2((acc[i][j][2] + bvv.z) * sc, (acc[i][j][3] + bvv.w) * sc);
                *(uint2*)(dst + (hb + n) * 32 + dc) = w;
            }
        }
    } else {
        #pragma unroll
        for (int j = 0; j < 4; ++j) {
            int dloc = wd + j * 16 + l16;
            int vd = d0 - 768 + dloc;
            int h = vd >> 5, dc = vd & 31;
            float bv = ballf[d0 + dloc];
            size_t hbase = (size_t)(b * NH_ + h) * 32768 + dc * 32;
            #pragma unroll
            for (int i = 0; i < 4; ++i) {
                int n = n0 + wn + i * 16 + quad * 4;
                size_t cbase = hbase + (size_t)((n >> 5)) * 1024 + (n & 31);
                uint2 w;
                w.x = pk2(acc[i][j][0] + bv, acc[i][j][1] + bv);
                w.y = pk2(acc[i][j][2] + bv, acc[i][j][3] + bv);
                *(uint2*)(Vtc + cbase) = w;
            }
        }
    }
}

// ---------------------------------------------------------------------------
// attn6: flash attention, S^T orientation; 1 q-strip/wave (64-q blocks).
// Bias C-operands from LDS-resident reversed Toeplitz table.
// rsum via ones-row MFMA (matrix pipe, lane-matched layout, no shuffles).
// K register-prefetched one chunk ahead. Straight-line chunk body (no array
// copies -> no v_mov waste).
// ---------------------------------------------------------------------------
__global__ __launch_bounds__(256, 4) void attn6(
    const ushort* __restrict__ Qt, const ushort* __restrict__ Kt,
    const ushort* __restrict__ Vtc, const float* __restrict__ tabT,
    ushort* __restrict__ O)
{
    const int bid = blockIdx.x;      // nx*96 + (b*12+h): same (b,h) -> same XCD
    const int bh96 = bid % 96;
    const int nx = bid / 96;         // 0..15
    const int b = bh96 / 12, h = bh96 % 12;

    __shared__ float tabL[TS_];
    __shared__ ushort Pa[4096];      // 4 waves x 16 x 64

    const int tid = threadIdx.x;
    const int lane = tid & 63, wave = tid >> 6;
    const int quad = lane >> 4, l16 = lane & 15;
    const int bh = b * NH_ + h;

    // vectorized table stage
    {
        const float* th = tabT + h * TS_;
        int i = tid * 4;
        #pragma unroll
        for (int k = 0; k < 4; ++k) {
            if (i < TS_) *(float4*)&tabL[i] = *(const float4*)&th[i];
            i += 1024;
        }
    }
    __syncthreads();

    const int qs = nx * 4 + wave;    // strip 0..63
    const int q = qs * 16 + l16;
    const ushort* Kbh = Kt + (size_t)bh * N_ * 32;
    const ushort* Vbh = Vtc + (size_t)bh * 16 * 2048;

    bf16x8 qf = *(const bf16x8*)(Qt + ((size_t)bh * N_ + q) * 32 + quad * 8);
    const int ibx = (31 - (q >> 5)) * 63 + (31 - (q & 31));

    bf16x8 ones;
    #pragma unroll
    for (int j = 0; j < 8; ++j) ones[j] = (__bf16)1.0f;

    f32x4 oacc0 = {}, oacc1 = {}, lacc = {};

    ushort* Pw = &Pa[wave * 1024];
    const int pswz = l16 & 0xE;
    const int pwr = l16 * 64;

    // K(0) preload
    const ushort* kp0 = Kbh + l16 * 32 + quad * 8;
    bf16x8 ka0 = *(const bf16x8*)(kp0);
    bf16x8 ka1 = *(const bf16x8*)(kp0 + 512);
    bf16x8 ka2 = *(const bf16x8*)(kp0 + 1024);
    bf16x8 ka3 = *(const bf16x8*)(kp0 + 1536);

    for (int mc = 0; mc < 16; ++mc) {
        // V(mc) loads (used late in chunk -> self-hiding)
        const ushort* vp = Vbh + mc * 2048 + l16 * 32 + quad * 8;
        bf16x8 va00 = *(const bf16x8*)(vp);             // kc=0, dt=0
        bf16x8 va01 = *(const bf16x8*)(vp + 512);       // kc=0, dt=1
        bf16x8 va10 = *(const bf16x8*)(vp + 1024);      // kc=1, dt=0
        bf16x8 va11 = *(const bf16x8*)(vp + 1536);      // kc=1, dt=1
        // K(mc+1) prefetch (wraps to chunk 0 at the end; harmless re-read)
        const ushort* kn = Kbh + ((mc + 1) & 15) * 2048 + l16 * 32 + quad * 8;
        bf16x8 kb0 = *(const bf16x8*)(kn);
        bf16x8 kb1 = *(const bf16x8*)(kn + 512);
        bf16x8 kb2 = *(const bf16x8*)(kn + 1024);
        bf16x8 kb3 = *(const bf16x8*)(kn + 1536);

        // bias C-operands (broadcast float4 windows, offsets {0,16,63,79})
        const float* Tb = tabL + ibx + mc * 126 + quad * 4;
        f32x4 cb0, cb1, cb2, cb3;
        #pragma unroll
        for (int e = 0; e < 4; ++e) {
            cb0[e] = Tb[e];
            cb1[e] = Tb[e + 16];
            cb2[e] = Tb[e + 63];
            cb3[e] = Tb[e + 79];
        }

        f32x4 s0 = __builtin_amdgcn_mfma_f32_16x16x32_bf16(ka0, qf, cb0, 0, 0, 0);
        f32x4 s1 = __builtin_amdgcn_mfma_f32_16x16x32_bf16(ka1, qf, cb1, 0, 0, 0);
        f32x4 s2 = __builtin_amdgcn_mfma_f32_16x16x32_bf16(ka2, qf, cb2, 0, 0, 0);
        f32x4 s3 = __builtin_amdgcn_mfma_f32_16x16x32_bf16(ka3, qf, cb3, 0, 0, 0);
        ka0 = kb0; ka1 = kb1; ka2 = kb2; ka3 = kb3;

        // p = exp2(s); pack to LDS in swizzled B-layout (no rsum VALU)
        {
            uint2 w;
            w.x = pk2(EXP2(s0[0]), EXP2(s0[1]));
            w.y = pk2(EXP2(s0[2]), EXP2(s0[3]));
            *(uint2*)(Pw + pwr + (((0 + quad) ^ pswz) * 4)) = w;
            w.x = pk2(EXP2(s1[0]), EXP2(s1[1]));
            w.y = pk2(EXP2(s1[2]), EXP2(s1[3]));
            *(uint2*)(Pw + pwr + (((4 + quad) ^ pswz) * 4)) = w;
            w.x = pk2(EXP2(s2[0]), EXP2(s2[1]));
            w.y = pk2(EXP2(s2[2]), EXP2(s2[3]));
            *(uint2*)(Pw + pwr + (((8 + quad) ^ pswz) * 4)) = w;
            w.x = pk2(EXP2(s3[0]), EXP2(s3[1]));
            w.y = pk2(EXP2(s3[2]), EXP2(s3[3]));
            *(uint2*)(Pw + pwr + (((12 + quad) ^ pswz) * 4)) = w;
        }

        // PV + ones-rowsum (all on matrix pipe)
        bf16x8 pb0 = *(const bf16x8*)(Pw + pwr + (((quad * 2) ^ pswz) * 4));
        lacc  = __builtin_amdgcn_mfma_f32_16x16x32_bf16(ones, pb0, lacc, 0, 0, 0);
        oacc0 = __builtin_amdgcn_mfma_f32_16x16x32_bf16(va00, pb0, oacc0, 0, 0, 0);
        oacc1 = __builtin_amdgcn_mfma_f32_16x16x32_bf16(va01, pb0, oacc1, 0, 0, 0);
        bf16x8 pb1 = *(const bf16x8*)(Pw + pwr + (((8 + quad * 2) ^ pswz) * 4));
        lacc  = __builtin_amdgcn_mfma_f32_16x16x32_bf16(ones, pb1, lacc, 0, 0, 0);
        oacc0 = __builtin_amdgcn_mfma_f32_16x16x32_bf16(va10, pb1, oacc0, 0, 0, 0);
        oacc1 = __builtin_amdgcn_mfma_f32_16x16x32_bf16(va11, pb1, oacc1, 0, 0, 0);
    }

    // lacc rows all equal = total rowsum for this lane's q
    float inv = 1.0f / lacc[0];

    ushort* ob = O + ((size_t)(b * N_ + q)) * C_ + h * HD_;
    uint2 w0, w1;
    w0.x = pk2(oacc0[0] * inv, oacc0[1] * inv);
    w0.y = pk2(oacc0[2] * inv, oacc0[3] * inv);
    *(uint2*)(ob + quad * 4) = w0;
    w1.x = pk2(oacc1[0] * inv, oacc1[1] * inv);
    w1.y = pk2(oacc1[2] * inv, oacc1[3] * inv);
    *(uint2*)(ob + 16 + quad * 4) = w1;
}

// ---------------------------------------------------------------------------
// proj_gemm3: 128x128 tile, global_load_lds. A=PW[d][c], B=O[n][c].
// out[b][d][n] fp32 = acc + pb[d], coalesced along n.
// ---------------------------------------------------------------------------
__global__ __launch_bounds__(256) void proj_gemm3(
    const ushort* __restrict__ O, const ushort* __restrict__ PW,
    const float* __restrict__ pb, float* __restrict__ out)
{
    const int b = blockIdx.z, n0 = blockIdx.x * 128, d0 = blockIdx.y * 128;
    __shared__ ushort As[128 * 32];
    __shared__ ushort Bs[128 * 32];
    const int tid = threadIdx.x;
    const int lane = tid & 63, wave = tid >> 6;
    const int quad = lane >> 4, l16 = lane & 15;
    const int wa = (wave & 1) * 64, wb = (wave >> 1) * 64;

    f32x4 acc[4][4] = {};
    const ushort* ab = PW + (size_t)d0 * C_;
    const ushort* bbp = O + ((size_t)b * N_ + n0) * C_;
    const int rowA = wave * 16 + (lane >> 2);
    const int fstage = ((lane >> 2) ^ (lane >> 4)) & 3;
    const int coff = ((lane & 3) ^ fstage) * 8;
    const int fread = ((l16 & 3) ^ ((l16 >> 2) & 3));

    for (int c0 = 0; c0 < C_; c0 += 32) {
        #pragma unroll
        for (int k = 0; k < 2; ++k) {
            gl2lds16(ab + (size_t)(k * 64 + rowA) * C_ + c0 + coff,
                     &As[(size_t)(k * 256 + wave * 64) * 8]);
            gl2lds16(bbp + (size_t)(k * 64 + rowA) * C_ + c0 + coff,
                     &Bs[(size_t)(k * 256 + wave * 64) * 8]);
        }
        __syncthreads();
        bf16x8 af[4], bfr[4];
        #pragma unroll
        for (int i = 0; i < 4; ++i)
            af[i] = *(const bf16x8*)&As[(wa + i * 16 + l16) * 32 + (quad ^ fread) * 8];
        #pragma unroll
        for (int j = 0; j < 4; ++j)
            bfr[j] = *(const bf16x8*)&Bs[(wb + j * 16 + l16) * 32 + (quad ^ fread) * 8];
        #pragma unroll
        for (int i = 0; i < 4; ++i)
            #pragma unroll
            for (int j = 0; j < 4; ++j)
                acc[i][j] = __builtin_amdgcn_mfma_f32_16x16x32_bf16(af[i], bfr[j], acc[i][j], 0, 0, 0);
        __syncthreads();
    }

    #pragma unroll
    for (int i = 0; i < 4; ++i) {
        #pragma unroll
        for (int r = 0; r < 4; ++r) {
            int d = d0 + wa + i * 16 + quad * 4 + r;
            float bv = pb[d];
            float* op = out + ((size_t)b * C_ + d) * N_ + n0 + wb;
            #pragma unroll
            for (int j = 0; j < 4; ++j)
                op[j * 16 + l16] = acc[i][j][r] + bv;
        }
    }
}

// ---------------------------------------------------------------------------
extern "C" void kernel_launch(void* const* d_in, const int* in_sizes, int n_in,
                              void* d_out, int out_size, void* d_ws, size_t ws_size,
                              hipStream_t stream)
{
    const float* x      = (const float*)d_in[0];
    const float* q_w    = (const float*)d_in[1];
    const float* q_b    = (const float*)d_in[2];
    const float* kv_w   = (const float*)d_in[3];
    const float* kv_b   = (const float*)d_in[4];
    const float* proj_w = (const float*)d_in[5];
    const float* proj_b = (const float*)d_in[6];
    const float* rpb    = (const float*)d_in[7];
    float* out = (float*)d_out;

    char* ws = (char*)d_ws;
    ushort* xT    = (ushort*)(ws);                       //  6,291,456
    ushort* Qt    = (ushort*)(ws +  6291456);            //  6,291,456
    ushort* Kt    = (ushort*)(ws + 12582912);            //  6,291,456
    ushort* Vtc   = (ushort*)(ws + 18874368);            //  6,291,456
    ushort* O     = (ushort*)(ws + 25165824);            //  6,291,456
    float*  tabT  = (float*) (ws + 31457280);            //    190,656 (12 x 3972 x 4)
    ushort* Wall  = (ushort*)(ws + 31647936);            //    884,736
    ushort* PW    = (ushort*)(ws + 32532672);            //    294,912
    float*  ballf = (float*) (ws + 32827584);            //      4,608

    setup      <<<dim3(1358), 256, 0, stream>>>(x, q_w, kv_w, proj_w, q_b, kv_b, rpb,
                                                xT, tabT, Wall, PW, ballf);
    qkv_gemm5  <<<dim3(8, 9, B_), 256, 0, stream>>>(xT, Wall, ballf, Qt, Kt, Vtc);
    attn6      <<<dim3(1536), 256, 0, stream>>>(Qt, Kt, Vtc, tabT, O);
    proj_gemm3 <<<dim3(8, 3, B_), 256, 0, stream>>>(O, PW, proj_b, out);
}

// Round 9
// 158.063 us; speedup vs baseline: 1.0687x; 1.0687x over previous
//
#include <hip/hip_runtime.h>
#include <hip/hip_bf16.h>

#define B_  8
#define C_  384
#define N_  1024
#define NH_ 12
#define HD_ 32
#define D3_ 1152   // 3*C

typedef __bf16 bf16x8 __attribute__((ext_vector_type(8)));
typedef __bf16 bf16x2 __attribute__((ext_vector_type(2)));
typedef float  f32x4  __attribute__((ext_vector_type(4)));

typedef const __attribute__((address_space(1))) unsigned int guint;
typedef __attribute__((address_space(3))) unsigned int luint;

__device__ __forceinline__ float b2f(ushort u) {
    return __uint_as_float(((unsigned int)u) << 16);
}
__device__ __forceinline__ ushort f2b(float f) {
    unsigned int i = __float_as_uint(f);
    unsigned int r = i + 0x7fffu + ((i >> 16) & 1u);  // RNE
    return (ushort)(r >> 16);
}
// packed fp32x2 -> bf16x2 (RNE)
__device__ __forceinline__ unsigned pk2(float a, float b) {
#if __has_builtin(__builtin_amdgcn_cvt_pk_bf16_f32)
    bf16x2 t = __builtin_amdgcn_cvt_pk_bf16_f32(a, b);
    return __builtin_bit_cast(unsigned, t);
#else
    return (unsigned)f2b(a) | ((unsigned)f2b(b) << 16);
#endif
}

#if __has_builtin(__builtin_amdgcn_exp2f)
#define EXP2 __builtin_amdgcn_exp2f
#else
#define EXP2 exp2f
#endif

__device__ __forceinline__ void gl2lds16(const void* g, void* l) {
    __builtin_amdgcn_global_load_lds((guint*)g, (luint*)l, 16, 0, 0);
}

#define C1_ 0.25505654204433796f   // scale * log2e
#define C2_ 1.4426950408889634f    // log2e
#define TS_ 3972                   // padded per-head table stride (16B-aligned)

// ---------------------------------------------------------------------------
// setup: x-transpose + weight conversion + bias-table prep.
// Grid: [0,768) xtrans, [768,1346) prep, [1346,1358) tabT.
// tabT[h][i] = rpb[3968-i][h] * log2e   (full 2D reversal == 1D reversal)
// ---------------------------------------------------------------------------
__global__ __launch_bounds__(256) void setup(
    const float* __restrict__ x, const float* __restrict__ q_w,
    const float* __restrict__ kv_w, const float* __restrict__ proj_w,
    const float* __restrict__ q_b, const float* __restrict__ kv_b,
    const float* __restrict__ tab,
    ushort* __restrict__ xT, float* __restrict__ tabT,
    ushort* __restrict__ Wall, ushort* __restrict__ PW,
    float* __restrict__ ballf)
{
    __shared__ ushort T[64 * 72];
    const int bx = blockIdx.x, tid = threadIdx.x;

    if (bx < 768) {
        // ---- xtrans: x[b][c][n] fp32 -> xT[b][n][c] bf16 ----
        int t = bx;
        int nx = t & 15, cy = (t >> 4) % 6, b = t / 96;
        int n0 = nx * 64, c0 = cy * 64;
        {
            int i = tid >> 2;            // c-local
            int ns = (tid & 3) * 16;     // n-local
            const float* src = x + ((size_t)b * C_ + c0 + i) * N_ + n0 + ns;
            #pragma unroll
            for (int k4 = 0; k4 < 4; ++k4) {
                float4 f = *(const float4*)(src + k4 * 4);
                T[(ns + k4 * 4 + 0) * 72 + i] = f2b(f.x);
                T[(ns + k4 * 4 + 1) * 72 + i] = f2b(f.y);
                T[(ns + k4 * 4 + 2) * 72 + i] = f2b(f.z);
                T[(ns + k4 * 4 + 3) * 72 + i] = f2b(f.w);
            }
        }
        __syncthreads();
        {
            int j = tid >> 2;            // n-local
            int cs = (tid & 3) * 16;     // c-local
            ushort* dst = xT + ((size_t)b * N_ + n0 + j) * C_ + c0 + cs;
            *(uint4*)dst       = *(const uint4*)&T[j * 72 + cs];
            *(uint4*)(dst + 8) = *(const uint4*)&T[j * 72 + cs + 8];
        }
    } else if (bx < 1346) {
        // ---- prep: weights fp32 -> bf16; bias concat fp32 ----
        const int NW4 = 110592, NP4 = 36864, NB4 = 288;
        int t = (bx - 768) * 256 + tid;
        if (t < NW4) {
            int e = t * 4;
            float4 f = (e < 147456) ? *(const float4*)(q_w + e)
                                    : *(const float4*)(kv_w + e - 147456);
            union { uint2 u; ushort s[4]; } o;
            o.u.x = pk2(f.x, f.y); o.u.y = pk2(f.z, f.w);
            *(uint2*)(Wall + e) = o.u;
        } else if (t < NW4 + NP4) {
            int e = (t - NW4) * 4;
            float4 f = *(const float4*)(proj_w + e);
            union { uint2 u; ushort s[4]; } o;
            o.u.x = pk2(f.x, f.y); o.u.y = pk2(f.z, f.w);
            *(uint2*)(PW + e) = o.u;
        } else if (t < NW4 + NP4 + NB4) {
            int e = (t - NW4 - NP4) * 4;
            float4 f = (e < 384) ? *(const float4*)(q_b + e)
                                 : *(const float4*)(kv_b + e - 384);
            *(float4*)(ballf + e) = f;
        }
    } else {
        // ---- tabT: per-head fully-reversed, log2e-scaled table ----
        int h = bx - 1346;
        for (int i = tid; i < 3969; i += 256)
            tabT[h * TS_ + i] = tab[(size_t)(3968 - i) * NH_ + h] * C2_;
        if (tid < 3) tabT[h * TS_ + 3969 + tid] = 0.0f;
    }
}

// ---------------------------------------------------------------------------
// qkv_gemm5: 128x128 tile, global_load_lds, XOR-swizzled LDS.
// Q/K blocks: W as A-operand (C rows = d) -> packed 8B stores to Qt/Kt[b][h][n][32].
// V blocks:   x as A-operand (C rows = n) -> fused-transpose packed stores to Vtc.
// Q pre-scaled by scale*log2e.
// ---------------------------------------------------------------------------
__global__ __launch_bounds__(256) void qkv_gemm5(
    const ushort* __restrict__ xT, const ushort* __restrict__ Wall,
    const float* __restrict__ ballf, ushort* __restrict__ Qt,
    ushort* __restrict__ Kt, ushort* __restrict__ Vtc)
{
    const int b = blockIdx.z, n0 = blockIdx.x * 128, d0 = blockIdx.y * 128;
    __shared__ ushort As[128 * 32];
    __shared__ ushort Bs[128 * 32];
    const int tid = threadIdx.x;
    const int lane = tid & 63, wave = tid >> 6;
    const int quad = lane >> 4, l16 = lane & 15;
    const int wn = (wave & 1) * 64, wd = (wave >> 1) * 64;

    f32x4 acc[4][4] = {};
    const ushort* xb = xT + ((size_t)b * N_ + n0) * C_;
    const ushort* wb = Wall + (size_t)d0 * C_;
    const int rowA = wave * 16 + (lane >> 2);
    const int fstage = ((lane >> 2) ^ (lane >> 4)) & 3;           // staging swizzle
    const int coff = ((lane & 3) ^ fstage) * 8;
    const int fread = ((l16 & 3) ^ ((l16 >> 2) & 3));             // read swizzle
    const bool isV = (d0 >= 768);

    for (int c0 = 0; c0 < C_; c0 += 32) {
        #pragma unroll
        for (int k = 0; k < 2; ++k) {
            gl2lds16(xb + (size_t)(k * 64 + rowA) * C_ + c0 + coff,
                     &As[(size_t)(k * 256 + wave * 64) * 8]);
            gl2lds16(wb + (size_t)(k * 64 + rowA) * C_ + c0 + coff,
                     &Bs[(size_t)(k * 256 + wave * 64) * 8]);
        }
        __syncthreads();
        bf16x8 af[4], bfr[4];
        #pragma unroll
        for (int i = 0; i < 4; ++i)
            af[i] = *(const bf16x8*)&As[(wn + i * 16 + l16) * 32 + (quad ^ fread) * 8];
        #pragma unroll
        for (int j = 0; j < 4; ++j)
            bfr[j] = *(const bf16x8*)&Bs[(wd + j * 16 + l16) * 32 + (quad ^ fread) * 8];
        if (!isV) {
            #pragma unroll
            for (int i = 0; i < 4; ++i)
                #pragma unroll
                for (int j = 0; j < 4; ++j)
                    acc[i][j] = __builtin_amdgcn_mfma_f32_16x16x32_bf16(bfr[i], af[j], acc[i][j], 0, 0, 0);
        } else {
            #pragma unroll
            for (int i = 0; i < 4; ++i)
                #pragma unroll
                for (int j = 0; j < 4; ++j)
                    acc[i][j] = __builtin_amdgcn_mfma_f32_16x16x32_bf16(af[i], bfr[j], acc[i][j], 0, 0, 0);
        }
        __syncthreads();
    }

    if (!isV) {
        ushort* dst = (d0 < 384) ? Qt : Kt;
        const float sc = (d0 < 384) ? C1_ : 1.0f;
        const int reg0 = (d0 < 384) ? 0 : 384;
        #pragma unroll
        for (int i = 0; i < 4; ++i) {
            int dloc = wd + i * 16;
            int dg = d0 - reg0 + dloc;
            int h = dg >> 5;
            int dc = (dg & 31) + quad * 4;
            float4 bvv = *(const float4*)(ballf + d0 + dloc + quad * 4);
            size_t hb = (size_t)(b * NH_ + h) * N_;
            #pragma unroll
            for (int j = 0; j < 4; ++j) {
                int n = n0 + wn + j * 16 + l16;
                uint2 w;
                w.x = pk2((acc[i][j][0] + bvv.x) * sc, (acc[i][j][1] + bvv.y) * sc);
                w.y = pk2((acc[i][j][2] + bvv.z) * sc, (acc[i][j][3] + bvv.w) * sc);
                *(uint2*)(dst + (hb + n) * 32 + dc) = w;
            }
        }
    } else {
        #pragma unroll
        for (int j = 0; j < 4; ++j) {
            int dloc = wd + j * 16 + l16;
            int vd = d0 - 768 + dloc;
            int h = vd >> 5, dc = vd & 31;
            float bv = ballf[d0 + dloc];
            size_t hbase = (size_t)(b * NH_ + h) * 32768 + dc * 32;
            #pragma unroll
            for (int i = 0; i < 4; ++i) {
                int n = n0 + wn + i * 16 + quad * 4;
                size_t cbase = hbase + (size_t)((n >> 5)) * 1024 + (n & 31);
                uint2 w;
                w.x = pk2(acc[i][j][0] + bv, acc[i][j][1] + bv);
                w.y = pk2(acc[i][j][2] + bv, acc[i][j][3] + bv);
                *(uint2*)(Vtc + cbase) = w;
            }
        }
    }
}

// ---------------------------------------------------------------------------
// attn7: flash attention, S^T orientation; 4 q-strips per wave (4x K/V reuse),
// 128-thread blocks, 768-block grid (nx*96+bh keeps (b,h) on one XCD).
// Bias as MFMA C-operand from LDS Toeplitz table; ones-MFMA rowsum;
// K register-prefetched; strips processed in pairs to bound live registers.
// NO second launch_bounds arg: VGPR cap below ~160 kills the prefetch (r8).
// ---------------------------------------------------------------------------
__global__ __launch_bounds__(128) void attn7(
    const ushort* __restrict__ Qt, const ushort* __restrict__ Kt,
    const ushort* __restrict__ Vtc, const float* __restrict__ tabT,
    ushort* __restrict__ O)
{
    const int bid = blockIdx.x;      // nx*96 + (b*12+h)
    const int bh96 = bid % 96;
    const int nx = bid / 96;         // 0..7
    const int b = bh96 / 12, h = bh96 % 12;

    __shared__ float tabL[TS_];
    __shared__ ushort Pa[8192];      // 2 waves x 4 strips x 16x64

    const int tid = threadIdx.x;     // 0..127
    const int lane = tid & 63, wave = tid >> 6;   // wave 0..1
    const int quad = lane >> 4, l16 = lane & 15;
    const int bh = b * NH_ + h;

    // table stage: 128 threads, float4
    {
        const float* th = tabT + h * TS_;
        for (int i = tid * 4; i < TS_; i += 512)
            *(float4*)&tabL[i] = *(const float4*)&th[i];
    }
    __syncthreads();

    const int qs0 = nx * 8 + wave * 4;           // first of 4 strips
    const ushort* Kbh = Kt + (size_t)bh * N_ * 32;
    const ushort* Vbh = Vtc + (size_t)bh * 16 * 2048;

    // Q B-frags + reversed-table bases, per strip
    bf16x8 qf[4];
    int ib[4];
    #pragma unroll
    for (int st = 0; st < 4; ++st) {
        int q = (qs0 + st) * 16 + l16;
        qf[st] = *(const bf16x8*)(Qt + ((size_t)bh * N_ + q) * 32 + quad * 8);
        ib[st] = (31 - (q >> 5)) * 63 + (31 - (q & 31));
    }

    bf16x8 ones;
    #pragma unroll
    for (int j = 0; j < 8; ++j) ones[j] = (__bf16)1.0f;

    f32x4 oacc[4][2] = {};
    f32x4 lacc[4] = {};

    ushort* PwW = &Pa[wave * 4096];
    const int pswz = l16 & 0xE;
    const int pwr = l16 * 64;

    // K(0) preload
    {
    }
    const ushort* kp0 = Kbh + l16 * 32 + quad * 8;
    bf16x8 ka0 = *(const bf16x8*)(kp0);
    bf16x8 ka1 = *(const bf16x8*)(kp0 + 512);
    bf16x8 ka2 = *(const bf16x8*)(kp0 + 1024);
    bf16x8 ka3 = *(const bf16x8*)(kp0 + 1536);

    for (int mc = 0; mc < 16; ++mc) {
        // V(mc) loads (used mid/late chunk)
        const ushort* vp = Vbh + mc * 2048 + l16 * 32 + quad * 8;
        bf16x8 va00 = *(const bf16x8*)(vp);
        bf16x8 va01 = *(const bf16x8*)(vp + 512);
        bf16x8 va10 = *(const bf16x8*)(vp + 1024);
        bf16x8 va11 = *(const bf16x8*)(vp + 1536);
        // K(mc+1) register prefetch
        const ushort* kn = Kbh + ((mc + 1) & 15) * 2048 + l16 * 32 + quad * 8;
        bf16x8 kb0 = *(const bf16x8*)(kn);
        bf16x8 kb1 = *(const bf16x8*)(kn + 512);
        bf16x8 kb2 = *(const bf16x8*)(kn + 1024);
        bf16x8 kb3 = *(const bf16x8*)(kn + 1536);

        #pragma unroll
        for (int sp = 0; sp < 2; ++sp) {
            // --- pair of strips: QK + softmax + P-store ---
            f32x4 s[2][4];
            #pragma unroll
            for (int u = 0; u < 2; ++u) {
                const int st = sp * 2 + u;
                const float* Tb = tabL + ib[st] + mc * 126 + quad * 4;
                f32x4 cb0, cb1, cb2, cb3;
                #pragma unroll
                for (int e = 0; e < 4; ++e) {
                    cb0[e] = Tb[e];
                    cb1[e] = Tb[e + 16];
                    cb2[e] = Tb[e + 63];
                    cb3[e] = Tb[e + 79];
                }
                s[u][0] = __builtin_amdgcn_mfma_f32_16x16x32_bf16(ka0, qf[st], cb0, 0, 0, 0);
                s[u][1] = __builtin_amdgcn_mfma_f32_16x16x32_bf16(ka1, qf[st], cb1, 0, 0, 0);
                s[u][2] = __builtin_amdgcn_mfma_f32_16x16x32_bf16(ka2, qf[st], cb2, 0, 0, 0);
                s[u][3] = __builtin_amdgcn_mfma_f32_16x16x32_bf16(ka3, qf[st], cb3, 0, 0, 0);
            }
            #pragma unroll
            for (int u = 0; u < 2; ++u) {
                const int st = sp * 2 + u;
                ushort* Pw = PwW + st * 1024;
                #pragma unroll
                for (int t = 0; t < 4; ++t) {
                    uint2 w;
                    w.x = pk2(EXP2(s[u][t][0]), EXP2(s[u][t][1]));
                    w.y = pk2(EXP2(s[u][t][2]), EXP2(s[u][t][3]));
                    *(uint2*)(Pw + pwr + (((t * 4 + quad) ^ pswz) * 4)) = w;
                }
            }
            // --- pair: P-load + rowsum/PV MFMAs ---
            #pragma unroll
            for (int u = 0; u < 2; ++u) {
                const int st = sp * 2 + u;
                ushort* Pw = PwW + st * 1024;
                bf16x8 pb0 = *(const bf16x8*)(Pw + pwr + (((quad * 2) ^ pswz) * 4));
                lacc[st]    = __builtin_amdgcn_mfma_f32_16x16x32_bf16(ones, pb0, lacc[st], 0, 0, 0);
                oacc[st][0] = __builtin_amdgcn_mfma_f32_16x16x32_bf16(va00, pb0, oacc[st][0], 0, 0, 0);
                oacc[st][1] = __builtin_amdgcn_mfma_f32_16x16x32_bf16(va01, pb0, oacc[st][1], 0, 0, 0);
                bf16x8 pb1 = *(const bf16x8*)(Pw + pwr + (((8 + quad * 2) ^ pswz) * 4));
                lacc[st]    = __builtin_amdgcn_mfma_f32_16x16x32_bf16(ones, pb1, lacc[st], 0, 0, 0);
                oacc[st][0] = __builtin_amdgcn_mfma_f32_16x16x32_bf16(va10, pb1, oacc[st][0], 0, 0, 0);
                oacc[st][1] = __builtin_amdgcn_mfma_f32_16x16x32_bf16(va11, pb1, oacc[st][1], 0, 0, 0);
            }
        }
        ka0 = kb0; ka1 = kb1; ka2 = kb2; ka3 = kb3;
    }

    // epilogue
    #pragma unroll
    for (int st = 0; st < 4; ++st) {
        float inv = 1.0f / lacc[st][0];
        int q = (qs0 + st) * 16 + l16;
        ushort* ob = O + ((size_t)(b * N_ + q)) * C_ + h * HD_;
        uint2 w0, w1;
        w0.x = pk2(oacc[st][0][0] * inv, oacc[st][0][1] * inv);
        w0.y = pk2(oacc[st][0][2] * inv, oacc[st][0][3] * inv);
        *(uint2*)(ob + quad * 4) = w0;
        w1.x = pk2(oacc[st][1][0] * inv, oacc[st][1][1] * inv);
        w1.y = pk2(oacc[st][1][2] * inv, oacc[st][1][3] * inv);
        *(uint2*)(ob + 16 + quad * 4) = w1;
    }
}

// ---------------------------------------------------------------------------
// proj_gemm4: 64d x 128n tiles -> 384 blocks (fills 256 CUs; old 192 didn't).
// A=PW[d][c] (64 rows), B=O[n][c] (128 rows), global_load_lds staging.
// out[b][d][n] fp32 = acc + pb[d], coalesced along n.
// ---------------------------------------------------------------------------
__global__ __launch_bounds__(256) void proj_gemm4(
    const ushort* __restrict__ O, const ushort* __restrict__ PW,
    const float* __restrict__ pb, float* __restrict__ out)
{
    const int b = blockIdx.z, n0 = blockIdx.x * 128, d0 = blockIdx.y * 64;
    __shared__ ushort As[64 * 32];    // PW tile
    __shared__ ushort Bs[128 * 32];   // O tile
    const int tid = threadIdx.x;
    const int lane = tid & 63, wave = tid >> 6;
    const int quad = lane >> 4, l16 = lane & 15;
    const int wd = (wave & 1) * 32, wn = (wave >> 1) * 64;

    f32x4 acc[2][4] = {};
    const ushort* ab = PW + (size_t)d0 * C_;
    const ushort* bbp = O + ((size_t)b * N_ + n0) * C_;
    const int rowA = wave * 16 + (lane >> 2);
    const int fstage = ((lane >> 2) ^ (lane >> 4)) & 3;
    const int coff = ((lane & 3) ^ fstage) * 8;
    const int fread = ((l16 & 3) ^ ((l16 >> 2) & 3));

    for (int c0 = 0; c0 < C_; c0 += 32) {
        // A: 64 rows in one round
        gl2lds16(ab + (size_t)rowA * C_ + c0 + coff, &As[(size_t)(wave * 64) * 8]);
        // B: 128 rows in two rounds
        #pragma unroll
        for (int k = 0; k < 2; ++k)
            gl2lds16(bbp + (size_t)(k * 64 + rowA) * C_ + c0 + coff,
                     &Bs[(size_t)(k * 256 + wave * 64) * 8]);
        __syncthreads();
        bf16x8 af[2], bfr[4];
        #pragma unroll
        for (int i = 0; i < 2; ++i)
            af[i] = *(const bf16x8*)&As[(wd + i * 16 + l16) * 32 + (quad ^ fread) * 8];
        #pragma unroll
        for (int j = 0; j < 4; ++j)
            bfr[j] = *(const bf16x8*)&Bs[(wn + j * 16 + l16) * 32 + (quad ^ fread) * 8];
        #pragma unroll
        for (int i = 0; i < 2; ++i)
            #pragma unroll
            for (int j = 0; j < 4; ++j)
                acc[i][j] = __builtin_amdgcn_mfma_f32_16x16x32_bf16(af[i], bfr[j], acc[i][j], 0, 0, 0);
        __syncthreads();
    }

    #pragma unroll
    for (int i = 0; i < 2; ++i) {
        #pragma unroll
        for (int r = 0; r < 4; ++r) {
            int d = d0 + wd + i * 16 + quad * 4 + r;
            float bv = pb[d];
            float* op = out + ((size_t)b * C_ + d) * N_ + n0 + wn;
            #pragma unroll
            for (int j = 0; j < 4; ++j)
                op[j * 16 + l16] = acc[i][j][r] + bv;
        }
    }
}

// ---------------------------------------------------------------------------
extern "C" void kernel_launch(void* const* d_in, const int* in_sizes, int n_in,
                              void* d_out, int out_size, void* d_ws, size_t ws_size,
                              hipStream_t stream)
{
    const float* x      = (const float*)d_in[0];
    const float* q_w    = (const float*)d_in[1];
    const float* q_b    = (const float*)d_in[2];
    const float* kv_w   = (const float*)d_in[3];
    const float* kv_b   = (const float*)d_in[4];
    const float* proj_w = (const float*)d_in[5];
    const float* proj_b = (const float*)d_in[6];
    const float* rpb    = (const float*)d_in[7];
    float* out = (float*)d_out;

    char* ws = (char*)d_ws;
    ushort* xT    = (ushort*)(ws);                       //  6,291,456
    ushort* Qt    = (ushort*)(ws +  6291456);            //  6,291,456
    ushort* Kt    = (ushort*)(ws + 12582912);            //  6,291,456
    ushort* Vtc   = (ushort*)(ws + 18874368);            //  6,291,456
    ushort* O     = (ushort*)(ws + 25165824);            //  6,291,456
    float*  tabT  = (float*) (ws + 31457280);            //    190,656 (12 x 3972 x 4)
    ushort* Wall  = (ushort*)(ws + 31647936);            //    884,736
    ushort* PW    = (ushort*)(ws + 32532672);            //    294,912
    float*  ballf = (float*) (ws + 32827584);            //      4,608

    setup      <<<dim3(1358), 256, 0, stream>>>(x, q_w, kv_w, proj_w, q_b, kv_b, rpb,
                                                xT, tabT, Wall, PW, ballf);
    qkv_gemm5  <<<dim3(8, 9, B_), 256, 0, stream>>>(xT, Wall, ballf, Qt, Kt, Vtc);
    attn7      <<<dim3(768), 128, 0, stream>>>(Qt, Kt, Vtc, tabT, O);
    proj_gemm4 <<<dim3(8, 6, B_), 256, 0, stream>>>(O, PW, proj_b, out);
}

// Round 10
// 154.395 us; speedup vs baseline: 1.0940x; 1.0238x over previous
//
#include <hip/hip_runtime.h>
#include <hip/hip_bf16.h>

#define B_  8
#define C_  384
#define N_  1024
#define NH_ 12
#define HD_ 32
#define D3_ 1152   // 3*C

typedef __bf16 bf16x8 __attribute__((ext_vector_type(8)));
typedef __bf16 bf16x2 __attribute__((ext_vector_type(2)));
typedef float  f32x4  __attribute__((ext_vector_type(4)));

typedef const __attribute__((address_space(1))) unsigned int guint;
typedef __attribute__((address_space(3))) unsigned int luint;

__device__ __forceinline__ float b2f(ushort u) {
    return __uint_as_float(((unsigned int)u) << 16);
}
__device__ __forceinline__ ushort f2b(float f) {
    unsigned int i = __float_as_uint(f);
    unsigned int r = i + 0x7fffu + ((i >> 16) & 1u);  // RNE
    return (ushort)(r >> 16);
}
// packed fp32x2 -> bf16x2 (RNE)
__device__ __forceinline__ unsigned pk2(float a, float b) {
#if __has_builtin(__builtin_amdgcn_cvt_pk_bf16_f32)
    bf16x2 t = __builtin_amdgcn_cvt_pk_bf16_f32(a, b);
    return __builtin_bit_cast(unsigned, t);
#else
    return (unsigned)f2b(a) | ((unsigned)f2b(b) << 16);
#endif
}

#if __has_builtin(__builtin_amdgcn_exp2f)
#define EXP2 __builtin_amdgcn_exp2f
#else
#define EXP2 exp2f
#endif

__device__ __forceinline__ void gl2lds16(const void* g, void* l) {
    __builtin_amdgcn_global_load_lds((guint*)g, (luint*)l, 16, 0, 0);
}

#define C1_ 0.25505654204433796f   // scale * log2e
#define C2_ 1.4426950408889634f    // log2e
#define TS_ 3972                   // padded per-head table stride (16B-aligned)

// ---------------------------------------------------------------------------
// setup: x-transpose + weight conversion + bias-table prep.
// Grid: [0,768) xtrans, [768,1346) prep, [1346,1358) tabT.
// tabT[h][i] = rpb[3968-i][h] * log2e   (full 2D reversal == 1D reversal)
// ---------------------------------------------------------------------------
__global__ __launch_bounds__(256) void setup(
    const float* __restrict__ x, const float* __restrict__ q_w,
    const float* __restrict__ kv_w, const float* __restrict__ proj_w,
    const float* __restrict__ q_b, const float* __restrict__ kv_b,
    const float* __restrict__ tab,
    ushort* __restrict__ xT, float* __restrict__ tabT,
    ushort* __restrict__ Wall, ushort* __restrict__ PW,
    float* __restrict__ ballf)
{
    __shared__ ushort T[64 * 72];
    const int bx = blockIdx.x, tid = threadIdx.x;

    if (bx < 768) {
        // ---- xtrans: x[b][c][n] fp32 -> xT[b][n][c] bf16 ----
        int t = bx;
        int nx = t & 15, cy = (t >> 4) % 6, b = t / 96;
        int n0 = nx * 64, c0 = cy * 64;
        {
            int i = tid >> 2;            // c-local
            int ns = (tid & 3) * 16;     // n-local
            const float* src = x + ((size_t)b * C_ + c0 + i) * N_ + n0 + ns;
            #pragma unroll
            for (int k4 = 0; k4 < 4; ++k4) {
                float4 f = *(const float4*)(src + k4 * 4);
                T[(ns + k4 * 4 + 0) * 72 + i] = f2b(f.x);
                T[(ns + k4 * 4 + 1) * 72 + i] = f2b(f.y);
                T[(ns + k4 * 4 + 2) * 72 + i] = f2b(f.z);
                T[(ns + k4 * 4 + 3) * 72 + i] = f2b(f.w);
            }
        }
        __syncthreads();
        {
            int j = tid >> 2;            // n-local
            int cs = (tid & 3) * 16;     // c-local
            ushort* dst = xT + ((size_t)b * N_ + n0 + j) * C_ + c0 + cs;
            *(uint4*)dst       = *(const uint4*)&T[j * 72 + cs];
            *(uint4*)(dst + 8) = *(const uint4*)&T[j * 72 + cs + 8];
        }
    } else if (bx < 1346) {
        // ---- prep: weights fp32 -> bf16; bias concat fp32 ----
        const int NW4 = 110592, NP4 = 36864, NB4 = 288;
        int t = (bx - 768) * 256 + tid;
        if (t < NW4) {
            int e = t * 4;
            float4 f = (e < 147456) ? *(const float4*)(q_w + e)
                                    : *(const float4*)(kv_w + e - 147456);
            union { uint2 u; ushort s[4]; } o;
            o.u.x = pk2(f.x, f.y); o.u.y = pk2(f.z, f.w);
            *(uint2*)(Wall + e) = o.u;
        } else if (t < NW4 + NP4) {
            int e = (t - NW4) * 4;
            float4 f = *(const float4*)(proj_w + e);
            union { uint2 u; ushort s[4]; } o;
            o.u.x = pk2(f.x, f.y); o.u.y = pk2(f.z, f.w);
            *(uint2*)(PW + e) = o.u;
        } else if (t < NW4 + NP4 + NB4) {
            int e = (t - NW4 - NP4) * 4;
            float4 f = (e < 384) ? *(const float4*)(q_b + e)
                                 : *(const float4*)(kv_b + e - 384);
            *(float4*)(ballf + e) = f;
        }
    } else {
        // ---- tabT: per-head fully-reversed, log2e-scaled table ----
        int h = bx - 1346;
        for (int i = tid; i < 3969; i += 256)
            tabT[h * TS_ + i] = tab[(size_t)(3968 - i) * NH_ + h] * C2_;
        if (tid < 3) tabT[h * TS_ + 3969 + tid] = 0.0f;
    }
}

// ---------------------------------------------------------------------------
// qkv_gemm5: 128x128 tile, global_load_lds, XOR-swizzled LDS.
// Q/K blocks: W as A-operand (C rows = d) -> packed 8B stores to Qt/Kt[b][h][n][32].
// V blocks:   x as A-operand (C rows = n) -> fused-transpose packed stores to Vtc.
// Q pre-scaled by scale*log2e.
// ---------------------------------------------------------------------------
__global__ __launch_bounds__(256) void qkv_gemm5(
    const ushort* __restrict__ xT, const ushort* __restrict__ Wall,
    const float* __restrict__ ballf, ushort* __restrict__ Qt,
    ushort* __restrict__ Kt, ushort* __restrict__ Vtc)
{
    const int b = blockIdx.z, n0 = blockIdx.x * 128, d0 = blockIdx.y * 128;
    __shared__ ushort As[128 * 32];
    __shared__ ushort Bs[128 * 32];
    const int tid = threadIdx.x;
    const int lane = tid & 63, wave = tid >> 6;
    const int quad = lane >> 4, l16 = lane & 15;
    const int wn = (wave & 1) * 64, wd = (wave >> 1) * 64;

    f32x4 acc[4][4] = {};
    const ushort* xb = xT + ((size_t)b * N_ + n0) * C_;
    const ushort* wb = Wall + (size_t)d0 * C_;
    const int rowA = wave * 16 + (lane >> 2);
    const int fstage = ((lane >> 2) ^ (lane >> 4)) & 3;           // staging swizzle
    const int coff = ((lane & 3) ^ fstage) * 8;
    const int fread = ((l16 & 3) ^ ((l16 >> 2) & 3));             // read swizzle
    const bool isV = (d0 >= 768);

    for (int c0 = 0; c0 < C_; c0 += 32) {
        #pragma unroll
        for (int k = 0; k < 2; ++k) {
            gl2lds16(xb + (size_t)(k * 64 + rowA) * C_ + c0 + coff,
                     &As[(size_t)(k * 256 + wave * 64) * 8]);
            gl2lds16(wb + (size_t)(k * 64 + rowA) * C_ + c0 + coff,
                     &Bs[(size_t)(k * 256 + wave * 64) * 8]);
        }
        __syncthreads();
        bf16x8 af[4], bfr[4];
        #pragma unroll
        for (int i = 0; i < 4; ++i)
            af[i] = *(const bf16x8*)&As[(wn + i * 16 + l16) * 32 + (quad ^ fread) * 8];
        #pragma unroll
        for (int j = 0; j < 4; ++j)
            bfr[j] = *(const bf16x8*)&Bs[(wd + j * 16 + l16) * 32 + (quad ^ fread) * 8];
        if (!isV) {
            #pragma unroll
            for (int i = 0; i < 4; ++i)
                #pragma unroll
                for (int j = 0; j < 4; ++j)
                    acc[i][j] = __builtin_amdgcn_mfma_f32_16x16x32_bf16(bfr[i], af[j], acc[i][j], 0, 0, 0);
        } else {
            #pragma unroll
            for (int i = 0; i < 4; ++i)
                #pragma unroll
                for (int j = 0; j < 4; ++j)
                    acc[i][j] = __builtin_amdgcn_mfma_f32_16x16x32_bf16(af[i], bfr[j], acc[i][j], 0, 0, 0);
        }
        __syncthreads();
    }

    if (!isV) {
        ushort* dst = (d0 < 384) ? Qt : Kt;
        const float sc = (d0 < 384) ? C1_ : 1.0f;
        const int reg0 = (d0 < 384) ? 0 : 384;
        #pragma unroll
        for (int i = 0; i < 4; ++i) {
            int dloc = wd + i * 16;
            int dg = d0 - reg0 + dloc;
            int h = dg >> 5;
            int dc = (dg & 31) + quad * 4;
            float4 bvv = *(const float4*)(ballf + d0 + dloc + quad * 4);
            size_t hb = (size_t)(b * NH_ + h) * N_;
            #pragma unroll
            for (int j = 0; j < 4; ++j) {
                int n = n0 + wn + j * 16 + l16;
                uint2 w;
                w.x = pk2((acc[i][j][0] + bvv.x) * sc, (acc[i][j][1] + bvv.y) * sc);
                w.y = pk2((acc[i][j][2] + bvv.z) * sc, (acc[i][j][3] + bvv.w) * sc);
                *(uint2*)(dst + (hb + n) * 32 + dc) = w;
            }
        }
    } else {
        #pragma unroll
        for (int j = 0; j < 4; ++j) {
            int dloc = wd + j * 16 + l16;
            int vd = d0 - 768 + dloc;
            int h = vd >> 5, dc = vd & 31;
            float bv = ballf[d0 + dloc];
            size_t hbase = (size_t)(b * NH_ + h) * 32768 + dc * 32;
            #pragma unroll
            for (int i = 0; i < 4; ++i) {
                int n = n0 + wn + i * 16 + quad * 4;
                size_t cbase = hbase + (size_t)((n >> 5)) * 1024 + (n & 31);
                uint2 w;
                w.x = pk2(acc[i][j][0] + bv, acc[i][j][1] + bv);
                w.y = pk2(acc[i][j][2] + bv, acc[i][j][3] + bv);
                *(uint2*)(Vtc + cbase) = w;
            }
        }
    }
}

// ---------------------------------------------------------------------------
// attn8: flash attention, S^T orientation, m-split across wave pairs.
// Block = 256 thr; waves (0,1) share strip-pair A (m-halves 0/1), waves (2,3)
// share pair B. Fixed-max softmax makes the merge pure addition (O, l).
// 1536 blocks -> ~16-20 waves/CU (TLP is the binding resource; r9 evidence).
// Bias as MFMA C-operand from LDS Toeplitz table; ones-MFMA rowsum.
// ---------------------------------------------------------------------------
__global__ __launch_bounds__(256) void attn8(
    const ushort* __restrict__ Qt, const ushort* __restrict__ Kt,
    const ushort* __restrict__ Vtc, const float* __restrict__ tabT,
    ushort* __restrict__ O)
{
    const int bid = blockIdx.x;      // nx*96 + (b*12+h); 96%8==0 -> same bh same XCD
    const int bh96 = bid % 96;
    const int nx = bid / 96;         // 0..15
    const int b = bh96 / 12, h = bh96 % 12;

    __shared__ float tabL[TS_];
    __shared__ ushort Pa[8192];      // 4 waves x 2 strips x 16x64; merge buf at end

    const int tid = threadIdx.x;
    const int lane = tid & 63, wave = tid >> 6;
    const int quad = lane >> 4, l16 = lane & 15;
    const int sp = wave >> 1;        // strip-pair 0/1
    const int mh = wave & 1;         // m-half 0/1
    const int bh = b * NH_ + h;

    // stage table (float4)
    {
        const float* th = tabT + h * TS_;
        for (int i = tid * 4; i < TS_; i += 1024)
            *(float4*)&tabL[i] = *(const float4*)&th[i];
    }
    __syncthreads();

    const int qs0 = nx * 4 + sp * 2;
    const ushort* Kbh = Kt + (size_t)bh * N_ * 32;
    const ushort* Vbh = Vtc + (size_t)bh * 16 * 2048;

    bf16x8 qf[2];
    int ib[2];
    #pragma unroll
    for (int st = 0; st < 2; ++st) {
        int q = (qs0 + st) * 16 + l16;
        qf[st] = *(const bf16x8*)(Qt + ((size_t)bh * N_ + q) * 32 + quad * 8);
        ib[st] = (31 - (q >> 5)) * 63 + (31 - (q & 31));
    }

    bf16x8 ones;
    #pragma unroll
    for (int j = 0; j < 8; ++j) ones[j] = (__bf16)1.0f;

    f32x4 oacc[2][2] = {};
    f32x4 lacc[2] = {};

    ushort* Pw0 = &Pa[wave * 2048];
    const int pswz = l16 & 0xE;
    const int pwr = l16 * 64;

    const int mc0 = mh * 8;
    // K(mc0) preload
    const ushort* kp0 = Kbh + mc0 * 2048 + l16 * 32 + quad * 8;
    bf16x8 ka0 = *(const bf16x8*)(kp0);
    bf16x8 ka1 = *(const bf16x8*)(kp0 + 512);
    bf16x8 ka2 = *(const bf16x8*)(kp0 + 1024);
    bf16x8 ka3 = *(const bf16x8*)(kp0 + 1536);

    for (int mc = mc0; mc < mc0 + 8; ++mc) {
        // V(mc) loads
        const ushort* vp = Vbh + mc * 2048 + l16 * 32 + quad * 8;
        bf16x8 va00 = *(const bf16x8*)(vp);
        bf16x8 va01 = *(const bf16x8*)(vp + 512);
        bf16x8 va10 = *(const bf16x8*)(vp + 1024);
        bf16x8 va11 = *(const bf16x8*)(vp + 1536);
        // K(mc+1) register prefetch (wrap keeps address valid; value unused)
        const ushort* kn = Kbh + ((mc + 1) & 15) * 2048 + l16 * 32 + quad * 8;
        bf16x8 kb0 = *(const bf16x8*)(kn);
        bf16x8 kb1 = *(const bf16x8*)(kn + 512);
        bf16x8 kb2 = *(const bf16x8*)(kn + 1024);
        bf16x8 kb3 = *(const bf16x8*)(kn + 1536);

        #pragma unroll
        for (int st = 0; st < 2; ++st) {
            const float* Tb = tabL + ib[st] + mc * 126 + quad * 4;
            f32x4 cb0, cb1, cb2, cb3;
            #pragma unroll
            for (int e = 0; e < 4; ++e) {
                cb0[e] = Tb[e];
                cb1[e] = Tb[e + 16];
                cb2[e] = Tb[e + 63];
                cb3[e] = Tb[e + 79];
            }
            f32x4 s0 = __builtin_amdgcn_mfma_f32_16x16x32_bf16(ka0, qf[st], cb0, 0, 0, 0);
            f32x4 s1 = __builtin_amdgcn_mfma_f32_16x16x32_bf16(ka1, qf[st], cb1, 0, 0, 0);
            f32x4 s2 = __builtin_amdgcn_mfma_f32_16x16x32_bf16(ka2, qf[st], cb2, 0, 0, 0);
            f32x4 s3 = __builtin_amdgcn_mfma_f32_16x16x32_bf16(ka3, qf[st], cb3, 0, 0, 0);

            ushort* Pw = Pw0 + st * 1024;
            uint2 w;
            w.x = pk2(EXP2(s0[0]), EXP2(s0[1]));
            w.y = pk2(EXP2(s0[2]), EXP2(s0[3]));
            *(uint2*)(Pw + pwr + (((0 + quad) ^ pswz) * 4)) = w;
            w.x = pk2(EXP2(s1[0]), EXP2(s1[1]));
            w.y = pk2(EXP2(s1[2]), EXP2(s1[3]));
            *(uint2*)(Pw + pwr + (((4 + quad) ^ pswz) * 4)) = w;
            w.x = pk2(EXP2(s2[0]), EXP2(s2[1]));
            w.y = pk2(EXP2(s2[2]), EXP2(s2[3]));
            *(uint2*)(Pw + pwr + (((8 + quad) ^ pswz) * 4)) = w;
            w.x = pk2(EXP2(s3[0]), EXP2(s3[1]));
            w.y = pk2(EXP2(s3[2]), EXP2(s3[3]));
            *(uint2*)(Pw + pwr + (((12 + quad) ^ pswz) * 4)) = w;

            bf16x8 pb0 = *(const bf16x8*)(Pw + pwr + (((quad * 2) ^ pswz) * 4));
            lacc[st]    = __builtin_amdgcn_mfma_f32_16x16x32_bf16(ones, pb0, lacc[st], 0, 0, 0);
            oacc[st][0] = __builtin_amdgcn_mfma_f32_16x16x32_bf16(va00, pb0, oacc[st][0], 0, 0, 0);
            oacc[st][1] = __builtin_amdgcn_mfma_f32_16x16x32_bf16(va01, pb0, oacc[st][1], 0, 0, 0);
            bf16x8 pb1 = *(const bf16x8*)(Pw + pwr + (((8 + quad * 2) ^ pswz) * 4));
            lacc[st]    = __builtin_amdgcn_mfma_f32_16x16x32_bf16(ones, pb1, lacc[st], 0, 0, 0);
            oacc[st][0] = __builtin_amdgcn_mfma_f32_16x16x32_bf16(va10, pb1, oacc[st][0], 0, 0, 0);
            oacc[st][1] = __builtin_amdgcn_mfma_f32_16x16x32_bf16(va11, pb1, oacc[st][1], 0, 0, 0);
        }
        ka0 = kb0; ka1 = kb1; ka2 = kb2; ka3 = kb3;
    }

    // ---- m-half merge (pure addition; fixed-max softmax) ----
    __syncthreads();                       // all P reads done; Pa reusable
    float* M = (float*)Pa;                 // [sp][18][64] floats = 9216 B
    if (mh) {
        #pragma unroll
        for (int st = 0; st < 2; ++st) {
            #pragma unroll
            for (int dt = 0; dt < 2; ++dt)
                #pragma unroll
                for (int e = 0; e < 4; ++e)
                    M[(sp * 18 + st * 8 + dt * 4 + e) * 64 + lane] = oacc[st][dt][e];
            M[(sp * 18 + 16 + st) * 64 + lane] = lacc[st][0];
        }
    }
    __syncthreads();
    if (!mh) {
        #pragma unroll
        for (int st = 0; st < 2; ++st) {
            float l = lacc[st][0] + M[(sp * 18 + 16 + st) * 64 + lane];
            float inv = 1.0f / l;
            int q = (qs0 + st) * 16 + l16;
            ushort* ob = O + ((size_t)(b * N_ + q)) * C_ + h * HD_;
            #pragma unroll
            for (int dt = 0; dt < 2; ++dt) {
                float v0 = oacc[st][dt][0] + M[(sp * 18 + st * 8 + dt * 4 + 0) * 64 + lane];
                float v1 = oacc[st][dt][1] + M[(sp * 18 + st * 8 + dt * 4 + 1) * 64 + lane];
                float v2 = oacc[st][dt][2] + M[(sp * 18 + st * 8 + dt * 4 + 2) * 64 + lane];
                float v3 = oacc[st][dt][3] + M[(sp * 18 + st * 8 + dt * 4 + 3) * 64 + lane];
                uint2 w;
                w.x = pk2(v0 * inv, v1 * inv);
                w.y = pk2(v2 * inv, v3 * inv);
                *(uint2*)(ob + dt * 16 + quad * 4) = w;
            }
        }
    }
}

// ---------------------------------------------------------------------------
// proj_gemm3: 128x128 tile, global_load_lds. A=PW[d][c], B=O[n][c].
// out[b][d][n] fp32 = acc + pb[d], coalesced along n.
// ---------------------------------------------------------------------------
__global__ __launch_bounds__(256) void proj_gemm3(
    const ushort* __restrict__ O, const ushort* __restrict__ PW,
    const float* __restrict__ pb, float* __restrict__ out)
{
    const int b = blockIdx.z, n0 = blockIdx.x * 128, d0 = blockIdx.y * 128;
    __shared__ ushort As[128 * 32];
    __shared__ ushort Bs[128 * 32];
    const int tid = threadIdx.x;
    const int lane = tid & 63, wave = tid >> 6;
    const int quad = lane >> 4, l16 = lane & 15;
    const int wa = (wave & 1) * 64, wb = (wave >> 1) * 64;

    f32x4 acc[4][4] = {};
    const ushort* ab = PW + (size_t)d0 * C_;
    const ushort* bbp = O + ((size_t)b * N_ + n0) * C_;
    const int rowA = wave * 16 + (lane >> 2);
    const int fstage = ((lane >> 2) ^ (lane >> 4)) & 3;
    const int coff = ((lane & 3) ^ fstage) * 8;
    const int fread = ((l16 & 3) ^ ((l16 >> 2) & 3));

    for (int c0 = 0; c0 < C_; c0 += 32) {
        #pragma unroll
        for (int k = 0; k < 2; ++k) {
            gl2lds16(ab + (size_t)(k * 64 + rowA) * C_ + c0 + coff,
                     &As[(size_t)(k * 256 + wave * 64) * 8]);
            gl2lds16(bbp + (size_t)(k * 64 + rowA) * C_ + c0 + coff,
                     &Bs[(size_t)(k * 256 + wave * 64) * 8]);
        }
        __syncthreads();
        bf16x8 af[4], bfr[4];
        #pragma unroll
        for (int i = 0; i < 4; ++i)
            af[i] = *(const bf16x8*)&As[(wa + i * 16 + l16) * 32 + (quad ^ fread) * 8];
        #pragma unroll
        for (int j = 0; j < 4; ++j)
            bfr[j] = *(const bf16x8*)&Bs[(wb + j * 16 + l16) * 32 + (quad ^ fread) * 8];
        #pragma unroll
        for (int i = 0; i < 4; ++i)
            #pragma unroll
            for (int j = 0; j < 4; ++j)
                acc[i][j] = __builtin_amdgcn_mfma_f32_16x16x32_bf16(af[i], bfr[j], acc[i][j], 0, 0, 0);
        __syncthreads();
    }

    #pragma unroll
    for (int i = 0; i < 4; ++i) {
        #pragma unroll
        for (int r = 0; r < 4; ++r) {
            int d = d0 + wa + i * 16 + quad * 4 + r;
            float bv = pb[d];
            float* op = out + ((size_t)b * C_ + d) * N_ + n0 + wb;
            #pragma unroll
            for (int j = 0; j < 4; ++j)
                op[j * 16 + l16] = acc[i][j][r] + bv;
        }
    }
}

// ---------------------------------------------------------------------------
extern "C" void kernel_launch(void* const* d_in, const int* in_sizes, int n_in,
                              void* d_out, int out_size, void* d_ws, size_t ws_size,
                              hipStream_t stream)
{
    const float* x      = (const float*)d_in[0];
    const float* q_w    = (const float*)d_in[1];
    const float* q_b    = (const float*)d_in[2];
    const float* kv_w   = (const float*)d_in[3];
    const float* kv_b   = (const float*)d_in[4];
    const float* proj_w = (const float*)d_in[5];
    const float* proj_b = (const float*)d_in[6];
    const float* rpb    = (const float*)d_in[7];
    float* out = (float*)d_out;

    char* ws = (char*)d_ws;
    ushort* xT    = (ushort*)(ws);                       //  6,291,456
    ushort* Qt    = (ushort*)(ws +  6291456);            //  6,291,456
    ushort* Kt    = (ushort*)(ws + 12582912);            //  6,291,456
    ushort* Vtc   = (ushort*)(ws + 18874368);            //  6,291,456
    ushort* O     = (ushort*)(ws + 25165824);            //  6,291,456
    float*  tabT  = (float*) (ws + 31457280);            //    190,656 (12 x 3972 x 4)
    ushort* Wall  = (ushort*)(ws + 31647936);            //    884,736
    ushort* PW    = (ushort*)(ws + 32532672);            //    294,912
    float*  ballf = (float*) (ws + 32827584);            //      4,608

    setup      <<<dim3(1358), 256, 0, stream>>>(x, q_w, kv_w, proj_w, q_b, kv_b, rpb,
                                                xT, tabT, Wall, PW, ballf);
    qkv_gemm5  <<<dim3(8, 9, B_), 256, 0, stream>>>(xT, Wall, ballf, Qt, Kt, Vtc);
    attn8      <<<dim3(1536), 256, 0, stream>>>(Qt, Kt, Vtc, tabT, O);
    proj_gemm3 <<<dim3(8, 3, B_), 256, 0, stream>>>(O, PW, proj_b, out);
}